// Round 5
// baseline (256.317 us; speedup 1.0000x reference)
//
#include <hip/hip_runtime.h>
#include <hip/hip_bf16.h>

// Problem constants (from reference)
#define TT 128   // time points
#define DD 64    // state dim
#define HH 256   // f-net hidden
#define HK 128   // kernel-net hidden
#define JH (TT*HK)      // 16384 contraction dim for G1
#define HD (HK*DD)      // 8192
#define NCHUNK 64       // jh chunks of 256 (= 2 j's each)

// ---------------------------------------------------------------------------
// shared MLP helper: ys(LDS) -> F[j], bF[j].  Uses hs/fs/red in LDS.
// All 256 threads of the block must enter (syncthreads inside).
// ---------------------------------------------------------------------------
__device__ __forceinline__ void mlp_from_ys(
    const float* __restrict__ ys, float* __restrict__ hs, float* __restrict__ fs,
    float (*red)[64],
    const float* __restrict__ W1, const float* __restrict__ b1,
    const float* __restrict__ W2, const float* __restrict__ b2,
    const float* __restrict__ bk2,
    float* __restrict__ F, float* __restrict__ bF, int j, int tid)
{
    int part = tid >> 6, d = tid & 63;
    // layer 1 (256 h, one per thread)
    float acc = b1[tid];
    #pragma unroll 8
    for (int e = 0; e < DD; ++e) acc += ys[e] * W1[e * HH + tid];
    hs[tid] = tanhf(acc);
    __syncthreads();
    // layer 2: 4-way split over h
    {
        float s = 0.f;
        #pragma unroll 8
        for (int h = part * 64; h < part * 64 + 64; ++h) s += hs[h] * W2[h * DD + d];
        red[part][d] = s;
    }
    __syncthreads();
    if (part == 0) {
        float a = b2[d] + red[0][d] + red[1][d] + red[2][d] + red[3][d];
        fs[d] = a;
        F[j * DD + d] = a;
    }
    __syncthreads();
    // bF: 4-way split over e
    {
        float s = 0.f;
        #pragma unroll
        for (int e = part * 16; e < part * 16 + 16; ++e) s += bk2[d * DD + e] * fs[e];
        red[part][d] = s;
    }
    __syncthreads();
    if (part == 0)
        bF[j * DD + d] = red[0][d] + red[1][d] + red[2][d] + red[3][d];
}

// ---------------------------------------------------------------------------
// k_prep: blocks [0,1024):    A[i, j*HK+h] = w(i,j)*tanh(...)
//         blocks [1024,1280): Wk2t[e*HD + h*DD + d] = Wk2[h, d*DD + e]
//         blocks [1280,1408): F-stage for it=0 (y=z0) + zero Gbuf0 row
// ---------------------------------------------------------------------------
__global__ void __launch_bounds__(256)
k_prep(const float* __restrict__ t, const float* __restrict__ Wk1,
       const float* __restrict__ bk1, const float* __restrict__ Wk2,
       const float* __restrict__ z0,
       const float* __restrict__ W1, const float* __restrict__ b1,
       const float* __restrict__ W2, const float* __restrict__ b2,
       const float* __restrict__ bk2,
       float* __restrict__ A, float* __restrict__ Wk2t,
       float* __restrict__ F, float* __restrict__ bF, float* __restrict__ G0) {
    __shared__ float tile[32][65];
    __shared__ float red[4][64];
    __shared__ float ys[DD];
    __shared__ float hs[HH];
    __shared__ float fs[DD];
    int b = blockIdx.x, tid = threadIdx.x;
    if (b < 1024) {
        float dt = t[1] - t[0];
        #pragma unroll
        for (int k = 0; k < 8; ++k) {
            int idx = b * 2048 + k * 256 + tid;
            int h = idx & 127, j = (idx >> 7) & 127, i = idx >> 14;
            float w = (i == 0 || j > i) ? 0.f : dt * ((j == 0 || j == i) ? 0.5f : 1.0f);
            float v = tanhf(t[i] * Wk1[h] + t[j] * Wk1[HK + h] + bk1[h]);
            A[idx] = w * v;
        }
    } else if (b < 1280) {
        int bb = b - 1024;
        int h = bb >> 1, dh = (bb & 1) * 32;
        for (int k = tid; k < 32 * 64; k += 256) {
            int d = k >> 6, e = k & 63;
            tile[d][e] = Wk2[(size_t)h * (DD * DD) + (size_t)(dh + d) * DD + e];
        }
        __syncthreads();
        for (int k = tid; k < 64 * 32; k += 256) {
            int e = k >> 5, d = k & 31;
            Wk2t[(size_t)e * HD + h * DD + dh + d] = tile[d][e];
        }
    } else {
        int j = b - 1280;
        if (tid < DD) { ys[tid] = z0[tid]; G0[j * DD + tid] = 0.f; }
        __syncthreads();
        mlp_from_ys(ys, hs, fs, red, W1, b1, W2, b2, bk2, F, bF, j, tid);
    }
}

// ---------------------------------------------------------------------------
// k_F (it>0): block j: y_j = z0 + dt*trap(Gr[0..j]); F[j]; bF[j].
// Also zeroes row j of Gz (the buffer the next k_G1 will accumulate into).
// ---------------------------------------------------------------------------
__global__ void __launch_bounds__(256)
k_F(const float* __restrict__ Gr, float* __restrict__ Gz,
    const float* __restrict__ z0, const float* __restrict__ t,
    const float* __restrict__ W1, const float* __restrict__ b1,
    const float* __restrict__ W2, const float* __restrict__ b2,
    const float* __restrict__ bk2,
    float* __restrict__ F, float* __restrict__ bF) {
    int j = blockIdx.x, tid = threadIdx.x;
    int part = tid >> 6, d = tid & 63;
    __shared__ float red[4][64];
    __shared__ float ys[DD];
    __shared__ float hs[HH];
    __shared__ float fs[DD];
    float dt = t[1] - t[0];
    if (tid < DD) Gz[j * DD + tid] = 0.f;
    float s = 0.f;
    if (j > 0) {
        for (int jp = part; jp <= j; jp += 4) {
            float w = (jp == 0 || jp == j) ? 0.5f : 1.0f;
            s += w * Gr[jp * DD + d];
        }
    }
    red[part][d] = s;
    __syncthreads();
    if (part == 0)
        ys[d] = z0[d] + dt * (red[0][d] + red[1][d] + red[2][d] + red[3][d]);
    __syncthreads();
    mlp_from_ys(ys, hs, fs, red, W1, b1, W2, b2, bk2, F, bF, j, tid);
}

// ---------------------------------------------------------------------------
// k_M: M[j*HD + hd] = sum_e F[j,e] * Wk2t[e*HD + hd]
// grid: (32 hd-chunks of 256, 16 j-chunks of 8), 256 threads, acc[8]
// ---------------------------------------------------------------------------
__global__ void __launch_bounds__(256)
k_M(const float* __restrict__ F, const float* __restrict__ Wk2t,
    float* __restrict__ M) {
    int tid = threadIdx.x;
    int hd = blockIdx.x * 256 + tid;
    int j0 = blockIdx.y * 8;
    __shared__ __attribute__((aligned(16))) float Fs[8][64];
    for (int k = tid; k < 8 * DD; k += 256) Fs[k >> 6][k & 63] = F[j0 * DD + k];
    __syncthreads();
    float acc[8];
    #pragma unroll
    for (int k = 0; k < 8; ++k) acc[k] = 0.f;
    const float* Wp = Wk2t + hd;
    for (int e = 0; e < DD; e += 8) {
        float w0 = Wp[(size_t)(e+0) * HD];
        float w1 = Wp[(size_t)(e+1) * HD];
        float w2 = Wp[(size_t)(e+2) * HD];
        float w3 = Wp[(size_t)(e+3) * HD];
        float w4 = Wp[(size_t)(e+4) * HD];
        float w5 = Wp[(size_t)(e+5) * HD];
        float w6 = Wp[(size_t)(e+6) * HD];
        float w7 = Wp[(size_t)(e+7) * HD];
        #pragma unroll
        for (int k = 0; k < 8; ++k) {
            float4 f0 = *(const float4*)&Fs[k][e];
            float4 f1 = *(const float4*)&Fs[k][e + 4];
            acc[k] += f0.x*w0 + f0.y*w1 + f0.z*w2 + f0.w*w3
                    + f1.x*w4 + f1.y*w5 + f1.z*w6 + f1.w*w7;
        }
    }
    #pragma unroll
    for (int k = 0; k < 8; ++k) M[(size_t)(j0 + k) * HD + hd] = acc[k];
}

// ---------------------------------------------------------------------------
// k_G1: chunk partial sums atomically accumulated into FULL G (Gout).
// grid: (16 itiles of 8 rows, 64 chunks of 256 jh); active iff c <= 4*itile+3.
// c==0 blocks additionally add the dt*trap(bF) term for their 8 rows.
// ---------------------------------------------------------------------------
__global__ void __launch_bounds__(256)
k_G1(const float* __restrict__ A, const float* __restrict__ M,
     const float* __restrict__ bF, const float* __restrict__ t,
     float* __restrict__ Gout) {
    int itile = blockIdx.x, c = blockIdx.y;
    if (c > 4 * itile + 3) return;   // chunk j-range entirely above row range
    __shared__ __attribute__((aligned(16))) float As[8 * 256];   // 8 KB
    __shared__ float red[4][8][64];                              // 8 KB
    int tid = threadIdx.x, sub = tid >> 6, d = tid & 63;
    {
        const float* Ab = A + (size_t)itile * 8 * JH + c * 256;
        float4* As4 = (float4*)As;
        #pragma unroll
        for (int k = 0; k < 2; ++k) {
            int idx = tid + k * 256;          // 512 float4
            int r = idx >> 6, q = idx & 63;
            As4[idx] = *(const float4*)(Ab + (size_t)r * JH + q * 4);
        }
    }
    __syncthreads();
    float acc[8] = {0.f,0.f,0.f,0.f,0.f,0.f,0.f,0.f};
    const float* Mp = M + ((size_t)c * 256) * DD + d;
    int jl0 = sub * 64;
    for (int jl = jl0; jl < jl0 + 64; jl += 8) {
        float m0 = Mp[(size_t)(jl + 0) * DD];
        float m1 = Mp[(size_t)(jl + 1) * DD];
        float m2 = Mp[(size_t)(jl + 2) * DD];
        float m3 = Mp[(size_t)(jl + 3) * DD];
        float m4 = Mp[(size_t)(jl + 4) * DD];
        float m5 = Mp[(size_t)(jl + 5) * DD];
        float m6 = Mp[(size_t)(jl + 6) * DD];
        float m7 = Mp[(size_t)(jl + 7) * DD];
        #pragma unroll
        for (int r = 0; r < 8; ++r) {
            float4 a0 = *(const float4*)&As[r * 256 + jl];
            float4 a1 = *(const float4*)&As[r * 256 + jl + 4];
            acc[r] += a0.x*m0 + a0.y*m1 + a0.z*m2 + a0.w*m3
                    + a1.x*m4 + a1.y*m5 + a1.z*m6 + a1.w*m7;
        }
    }
    #pragma unroll
    for (int r = 0; r < 8; ++r) red[sub][r][d] = acc[r];
    __syncthreads();
    if (sub == 0) {
        #pragma unroll
        for (int r = 0; r < 8; ++r) {
            float v = red[0][r][d] + red[1][r][d] + red[2][r][d] + red[3][r][d];
            atomicAdd(&Gout[(itile * 8 + r) * DD + d], v);
        }
        // bF trapezoid term, added once per row by the c==0 block
        if (c == 0) {
            float dt = t[1] - t[0];
            int jbase = itile * 8;
            float b0 = 0.5f * bF[d];
            float rs = 0.f;                      // sum_{p=1}^{jcur-1} bF[p,d]
            for (int p = 1; p < jbase; ++p) rs += bF[p * DD + d];
            #pragma unroll
            for (int r = 0; r < 8; ++r) {
                int j = jbase + r;
                float bj = bF[j * DD + d];
                if (j > 0) {
                    float val = dt * (b0 + rs + 0.5f * bj);
                    atomicAdd(&Gout[j * DD + d], val);
                    rs += bj;
                }
            }
        }
    }
}

// ---------------------------------------------------------------------------
// k_out: out[d] = z0[d] + dt * trap(G[0..T-1], d)
// ---------------------------------------------------------------------------
__global__ void __launch_bounds__(256)
k_out(const float* __restrict__ G, const float* __restrict__ z0,
      const float* __restrict__ t, float* __restrict__ out) {
    int tid = threadIdx.x, part = tid >> 6, d = tid & 63;
    __shared__ float red[4][64];
    float dt = t[1] - t[0];
    float s = 0.f;
    for (int j = part; j < TT; j += 4) {
        float w = (j == 0 || j == TT - 1) ? 0.5f : 1.0f;
        s += w * G[j * DD + d];
    }
    red[part][d] = s;
    __syncthreads();
    if (part == 0)
        out[d] = z0[d] + dt * (red[0][d] + red[1][d] + red[2][d] + red[3][d]);
}

extern "C" void kernel_launch(void* const* d_in, const int* in_sizes, int n_in,
                              void* d_out, int out_size, void* d_ws, size_t ws_size,
                              hipStream_t stream) {
    const float* z0  = (const float*)d_in[0];
    const float* t   = (const float*)d_in[1];
    const float* W1  = (const float*)d_in[2];
    const float* b1  = (const float*)d_in[3];
    const float* W2  = (const float*)d_in[4];
    const float* b2  = (const float*)d_in[5];
    const float* Wk1 = (const float*)d_in[6];
    const float* bk1 = (const float*)d_in[7];
    const float* Wk2 = (const float*)d_in[8];
    const float* bk2 = (const float*)d_in[9];
    float* out = (float*)d_out;

    float* ws   = (float*)d_ws;
    float* A    = ws;                       // T*T*HK   = 2,097,152
    float* Wk2t = A    + (size_t)TT*TT*HK;  // HK*D*D   =   524,288
    float* M    = Wk2t + (size_t)HK*DD*DD;  // T*HK*D   = 1,048,576
    float* F    = M    + (size_t)TT*HK*DD;  // T*D
    float* bF   = F    + TT*DD;             // T*D
    float* Gb0  = bF   + TT*DD;             // T*D (double buffer 0)
    float* Gb1  = Gb0  + TT*DD;             // T*D (double buffer 1)

    // prep: A, Wk2t, F(it=0), zero Gb0           [1 launch]
    k_prep<<<1408, 256, 0, stream>>>(t, Wk1, bk1, Wk2, z0,
                                     W1, b1, W2, b2, bk2, A, Wk2t, F, bF, Gb0);

    float* Gbuf[2] = { Gb0, Gb1 };
    for (int it = 0; it < 3; ++it) {
        float* Gacc = Gbuf[it & 1];          // k_G1 accumulates here
        if (it > 0) {
            float* Gprev = Gbuf[(it + 1) & 1];
            k_F<<<TT, 256, 0, stream>>>(Gprev, Gacc, z0, t, W1, b1, W2, b2, bk2, F, bF);
        }
        k_M<<<dim3(32, 16), 256, 0, stream>>>(F, Wk2t, M);
        k_G1<<<dim3(16, NCHUNK), 256, 0, stream>>>(A, M, bF, t, Gacc);
    }
    // after it=2, full G is in Gb0
    k_out<<<1, 256, 0, stream>>>(Gb0, z0, t, out);
}